// Round 17
// baseline (233.510 us; speedup 1.0000x reference)
//
#include <hip/hip_runtime.h>
#include <hip/hip_bf16.h>

constexpr int N_  = 12288;
constexpr int E_  = 393216;
constexpr int IND = 128;
constexpr int HID = 64;
constexpr int QKD = 32;
constexpr int CAP = 96;   // bucket capacity per node (mean deg 32, sigma 5.7)

typedef __attribute__((ext_vector_type(4))) float f4raw;
typedef __attribute__((ext_vector_type(8))) __bf16 bf16x8;
typedef __attribute__((ext_vector_type(4))) __bf16 bf16x4;
typedef __attribute__((ext_vector_type(16))) float f32x16;

// LDS bf16 tile helpers, 128B rows, XOR-swizzled (byte ^= (row&7)<<4).
__device__ inline bf16x8 lds_read_bf8(const char* base, int row, int k) {
  int off = (row * 128 + k * 2) ^ ((row & 7) << 4);
  uint4 u = *(const uint4*)(base + off);
  union { uint4 u; bf16x8 v; } c; c.u = u; return c.v;
}
__device__ inline void lds_write_bf(char* base, int row, int col, __bf16 v) {
  int off = (row * 128 + col * 2) ^ ((row & 7) << 4);
  *(__bf16*)(base + off) = v;
}
// 256B-row variants (for [64][128] bf16 W1 tile)
__device__ inline bf16x8 lds_read_bf8_256(const char* base, int row, int k) {
  int off = (row * 256 + k * 2) ^ ((row & 7) << 4);
  uint4 u = *(const uint4*)(base + off);
  union { uint4 u; bf16x8 v; } c; c.u = u; return c.v;
}
__device__ inline void lds_write_bf_256(char* base, int row, int col, __bf16 v) {
  int off = (row * 256 + col * 2) ^ ((row & 7) << 4);
  *(__bf16*)(base + off) = v;
}

// ---------------- K12: hist || scatter || WvT prep || Wvdx fold || MFMA encoder ----------------
// blocks [0,384): hist; [384,768): scatter; 768: WvT; 769: WvdxT+bvdx; [770,1154): encoder.
__global__ __launch_bounds__(256) void fused_front_kernel(
    const float* __restrict__ xo, const float* __restrict__ xt,
    const int* __restrict__ row, const int* __restrict__ col,
    const float* __restrict__ W1, const float* __restrict__ b1,
    const float* __restrict__ W2, const float* __restrict__ b2,
    const float* __restrict__ Wv, const float* __restrict__ bv,
    const float* __restrict__ Wdx, const float* __restrict__ bdx,
    const unsigned char* __restrict__ mask,
    __bf16* __restrict__ WvT, __bf16* __restrict__ WvdxT, float* __restrict__ bvdx,
    float* __restrict__ h_tr, float* __restrict__ gsum,
    int* degRow, int* cntCol, int* __restrict__ csrRow) {
  __shared__ __align__(16) char smem[33024];
  int b = blockIdx.x, tid = threadIdx.x;
  if (b < 384) {
    int e0 = (b * 256 + tid) * 4;
    int4 r4 = *(const int4*)(row + e0);
    atomicAdd(&degRow[r4.x], 1);
    atomicAdd(&degRow[r4.y], 1);
    atomicAdd(&degRow[r4.z], 1);
    atomicAdd(&degRow[r4.w], 1);
    return;
  }
  if (b < 768) {
    int e0 = ((b - 384) * 256 + tid) * 4;
    int4 r4 = *(const int4*)(row + e0);
    int4 c4 = *(const int4*)(col + e0);
    int p;
    p = atomicAdd(&cntCol[c4.x], 1); csrRow[c4.x * CAP + p] = r4.x;
    p = atomicAdd(&cntCol[c4.y], 1); csrRow[c4.y * CAP + p] = r4.y;
    p = atomicAdd(&cntCol[c4.z], 1); csrRow[c4.z * CAP + p] = r4.z;
    p = atomicAdd(&cntCol[c4.w], 1); csrRow[c4.w * CAP + p] = r4.w;
    return;
  }
  if (b == 768) {
    for (int e = tid; e < HID * HID; e += 256) {
      int c = e >> 6, k = e & 63;
      WvT[e] = (__bf16)Wv[k * HID + c];
    }
    return;
  }
  if (b == 769) {
    // WvdxT[c*64+k] = sum_j Wv[k][j] * Wdx[j][c]; Wdx staged in LDS (32 KB),
    // Wv reads are group-uniform (broadcast, L1-hit). bvdx = bv@Wdx + bdx.
    float* Wdxs = (float*)smem;                 // [64][128] fp32
    for (int e = tid; e < HID * IND; e += 256) Wdxs[e] = Wdx[e];
    __syncthreads();
    for (int e = tid; e < HID * IND; e += 256) {
      int k = e >> 7, c = e & 127;              // k fixed per 64-lane group
      float a = 0.f;
#pragma unroll 8
      for (int j = 0; j < HID; ++j) a = fmaf(Wv[k * HID + j], Wdxs[j * IND + c], a);
      WvdxT[c * HID + k] = (__bf16)a;
    }
    if (tid < IND) {
      float a = bdx[tid];
      for (int j = 0; j < HID; ++j) a = fmaf(bv[j], Wdxs[j * IND + tid], a);
      bvdx[tid] = a;
    }
    return;
  }
  // ---------------- encoder ----------------
  char* W1s = smem;                              // 16384 B
  char* W2s = smem + 16384;                      // 8192 B
  char* h1s0 = smem + 24576;                     // 4096 B
  char* h1s1 = smem + 28672;                     // 4096 B
  float* wls = (float*)(smem + 32768);           // 256 B
  int bb = b - 770;
  bool ori = bb < 192;
  int row0 = (ori ? bb : bb - 192) * 64;
  const float* xrow = (ori ? xo : xt) + (size_t)row0 * IND;
  for (int e = tid; e < IND * HID; e += 256) {
    int k = e >> 6, c = e & 63;                 // W1[e] = W1[k][c]
    lds_write_bf_256(W1s, c, k, (__bf16)W1[e]);
  }
  for (int e = tid; e < HID * HID; e += 256) {
    int k = e >> 6, c = e & 63;
    lds_write_bf(W2s, c, k, (__bf16)W2[e]);
  }
  if (ori && tid < 64) wls[tid] = mask[row0 + tid] ? 0.f : 1.f;
  __syncthreads();
  int wave = tid >> 6, lane = tid & 63;
  int p = wave >> 1, w2 = wave & 1;
  int lr = lane & 31, hi = lane >> 5;
  int colc = w2 * 32 + lr;
  char* h1p = p ? h1s1 : h1s0;
  f32x16 acc = (f32x16)(0.f);
  const float* arow = xrow + (size_t)(p * 32 + lr) * IND + hi * 8;
#pragma unroll
  for (int kk = 0; kk < 8; ++kk) {
    f4raw v0 = *(const f4raw*)(arow + kk * 16);
    f4raw v1 = *(const f4raw*)(arow + kk * 16 + 4);
    bf16x8 a;
    a[0] = (__bf16)v0.x; a[1] = (__bf16)v0.y; a[2] = (__bf16)v0.z; a[3] = (__bf16)v0.w;
    a[4] = (__bf16)v1.x; a[5] = (__bf16)v1.y; a[6] = (__bf16)v1.z; a[7] = (__bf16)v1.w;
    bf16x8 bq = lds_read_bf8_256(W1s, colc, kk * 16 + hi * 8);
    acc = __builtin_amdgcn_mfma_f32_32x32x16_bf16(a, bq, acc, 0, 0, 0);
  }
  float b1l = b1[colc];
#pragma unroll
  for (int reg = 0; reg < 16; ++reg) {
    int rr = (reg & 3) + 8 * (reg >> 2) + 4 * hi;
    float v = fmaxf(acc[reg] + b1l, 0.f);
    lds_write_bf(h1p, rr, colc, (__bf16)v);
  }
  __syncthreads();
  f32x16 acc2 = (f32x16)(0.f);
#pragma unroll
  for (int kk = 0; kk < 4; ++kk) {
    bf16x8 a = lds_read_bf8(h1p, lr, kk * 16 + hi * 8);
    bf16x8 bq = lds_read_bf8(W2s, colc, kk * 16 + hi * 8);
    acc2 = __builtin_amdgcn_mfma_f32_32x32x16_bf16(a, bq, acc2, 0, 0, 0);
  }
  float b2l = b2[colc];
  if (ori) {
    float part = 0.f;
#pragma unroll
    for (int reg = 0; reg < 16; ++reg) {
      int rr = (reg & 3) + 8 * (reg >> 2) + 4 * hi;
      float v = fmaxf(acc2[reg] + b2l, 0.f);
      part = fmaf(wls[p * 32 + rr], v, part);
    }
    atomicAdd(&gsum[colc], part);
    if (tid == 0) {
      float wl = 0.f;
      for (int r = 0; r < 64; ++r) wl += wls[r];
      atomicAdd(&gsum[64], wl);
    }
  } else {
#pragma unroll
    for (int reg = 0; reg < 16; ++reg) {
      int rr = (reg & 3) + 8 * (reg >> 2) + 4 * hi;
      float v = fmaxf(acc2[reg] + b2l, 0.f);
      h_tr[(size_t)(row0 + p * 32 + rr) * HID + colc] = v;
    }
  }
}

// ---------------- K3: lap1d = (h - sum(h[r]*dinv[r])*d)*d ; emits dinv ----------------
__global__ __launch_bounds__(256) void lap1_kernel(
    const float* __restrict__ h, const int* __restrict__ degRow,
    const int* __restrict__ cnt, const int* __restrict__ csrRow,
    float* __restrict__ lap1d, float* __restrict__ dinv) {
  int lane = threadIdx.x & 63, wv = threadIdx.x >> 6;
  int g = lane >> 4, t = lane & 15;
  int c = blockIdx.x * 16 + wv * 4 + g;
  int s0 = c * CAP, s1 = s0 + cnt[c];
  f4raw a0 = (f4raw)(0.f), a1 = (f4raw)(0.f), a2 = (f4raw)(0.f), a3 = (f4raw)(0.f);
  int i = s0;
  for (; i + 3 < s1; i += 4) {
    int r0 = csrRow[i], r1 = csrRow[i + 1], r2 = csrRow[i + 2], r3 = csrRow[i + 3];
    float d0 = rsqrtf((float)max(degRow[r0], 1));
    float d1 = rsqrtf((float)max(degRow[r1], 1));
    float d2 = rsqrtf((float)max(degRow[r2], 1));
    float d3 = rsqrtf((float)max(degRow[r3], 1));
    a0 += (*(const f4raw*)(h + (size_t)r0 * HID + t * 4)) * d0;
    a1 += (*(const f4raw*)(h + (size_t)r1 * HID + t * 4)) * d1;
    a2 += (*(const f4raw*)(h + (size_t)r2 * HID + t * 4)) * d2;
    a3 += (*(const f4raw*)(h + (size_t)r3 * HID + t * 4)) * d3;
  }
  for (; i < s1; ++i) {
    int r0 = csrRow[i];
    float d0 = rsqrtf((float)max(degRow[r0], 1));
    a0 += (*(const f4raw*)(h + (size_t)r0 * HID + t * 4)) * d0;
  }
  float d = rsqrtf((float)max(degRow[c], 1));
  if (t == 0) dinv[c] = d;
  size_t idx = (size_t)c * HID + t * 4;
  f4raw hc = *(const f4raw*)(h + idx);
  *(f4raw*)(lap1d + idx) = (hc - ((a0 + a1) + (a2 + a3)) * d) * d;
}

// ---------------- K4: lap2-gather + qfinal + attention + {z->zb (w0-1) || x_hat (w2-5)} ----------------
__global__ __launch_bounds__(512) void lap2_attnz_xhat_kernel(
    const float* __restrict__ h, const float* __restrict__ lap1d,
    const float* __restrict__ dinv,
    const int* __restrict__ cnt, const int* __restrict__ csrRow,
    const float* __restrict__ gsum,
    const float* __restrict__ Wq, const float* __restrict__ bq,
    const float* __restrict__ Wk, const float* __restrict__ bk,
    const __bf16* __restrict__ WvT, const float* __restrict__ bv,
    const __bf16* __restrict__ WvdxT, const float* __restrict__ bvdx,
    float* __restrict__ xhat, __bf16* __restrict__ zb) {
  __shared__ float l2s[32][68];
  __shared__ __align__(16) char zps[32 * 128];
  __shared__ float qg[QKD];
  __shared__ float kqs[72];
  int tid = threadIdx.x;
  int row0 = blockIdx.x * 32;
  float wsum = gsum[64];
  if (tid < QKD) {
    float inv = 1.0f / fmaxf(wsum, 1.0f);
    float a = bq[tid] * wsum;
    for (int d0 = 0; d0 < HID; ++d0) a = fmaf(gsum[d0], Wq[d0 * QKD + tid], a);
    qg[tid] = a * inv;
  }
  int grp = tid >> 4, t = tid & 15;   // 32 groups x 16 lanes
  {
    int r = grp;
    int c = row0 + r;
    int s0 = c * CAP, s1 = s0 + cnt[c];
    f4raw a0 = (f4raw)(0.f), a1 = (f4raw)(0.f), a2 = (f4raw)(0.f), a3 = (f4raw)(0.f);
    int i = s0;
    for (; i + 3 < s1; i += 4) {
      int r0 = csrRow[i], r1 = csrRow[i + 1], r2 = csrRow[i + 2], r3 = csrRow[i + 3];
      a0 += *(const f4raw*)(lap1d + (size_t)r0 * HID + t * 4);
      a1 += *(const f4raw*)(lap1d + (size_t)r1 * HID + t * 4);
      a2 += *(const f4raw*)(lap1d + (size_t)r2 * HID + t * 4);
      a3 += *(const f4raw*)(lap1d + (size_t)r3 * HID + t * 4);
    }
    for (; i < s1; ++i) {
      int r0 = csrRow[i];
      a0 += *(const f4raw*)(lap1d + (size_t)r0 * HID + t * 4);
    }
    float d = dinv[c];
    float rd = 1.0f / d;
    f4raw lv = *(const f4raw*)(lap1d + (size_t)c * HID + t * 4);
    *(f4raw*)&l2s[r][t * 4] = lv * rd - ((a0 + a1) + (a2 + a3)) * d;
  }
  __syncthreads();
  if (tid < 64) {
    float a = 0.f;
    for (int q = 0; q < QKD; ++q) a = fmaf(Wk[tid * QKD + q], qg[q], a);
    kqs[tid] = a * 0.125f;
  } else if (tid == 64) {
    float sb = 0.f;
    for (int q = 0; q < QKD; ++q) sb = fmaf(bk[q], qg[q], sb);
    kqs[64] = sb * 0.125f;
  }
  __syncthreads();
  {
    f4raw kq4 = *(const f4raw*)(&kqs[t * 4]);
    float sbias = kqs[64];
    int r = grp;
    int c = row0 + r;
    size_t idx = (size_t)c * HID + t * 4;
    float d = dinv[c];
    float rd = 1.0f / d;
    f4raw hv = *(const f4raw*)(h + idx);
    f4raw v1 = *(const f4raw*)(lap1d + idx) * rd;
    f4raw v2 = *(const f4raw*)&l2s[r][t * 4];
    f4raw av = 2.f * hv - v1;
    float s0 = av.x * kq4.x + av.y * kq4.y + av.z * kq4.z + av.w * kq4.w;
    float s1 = v1.x * kq4.x + v1.y * kq4.y + v1.z * kq4.z + v1.w * kq4.w;
    float s2 = v2.x * kq4.x + v2.y * kq4.y + v2.z * kq4.z + v2.w * kq4.w;
#pragma unroll
    for (int o = 1; o < 16; o <<= 1) {
      s0 += __shfl_xor(s0, o);
      s1 += __shfl_xor(s1, o);
      s2 += __shfl_xor(s2, o);
    }
    s0 += sbias; s1 += sbias; s2 += sbias;
    float m = fmaxf(s0, fmaxf(s1, s2));
    float e0 = __expf(s0 - m), e1 = __expf(s1 - m), e2 = __expf(s2 - m);
    float is = 1.f / (e0 + e1 + e2);
    f4raw zp = (e0 * av + e1 * v1 + e2 * v2) * is;
    bf16x4 z4;
    z4[0] = (__bf16)zp.x; z4[1] = (__bf16)zp.y; z4[2] = (__bf16)zp.z; z4[3] = (__bf16)zp.w;
    int off = (r * 128 + t * 8) ^ ((r & 7) << 4);
    *(bf16x4*)(zps + off) = z4;
  }
  __syncthreads();
  int wave = tid >> 6, lane = tid & 63;
  int lr = lane & 31, hi = lane >> 5;
  if (wave < 2) {
    // z = zp@Wv + bv -> zb (adj input)
    int col = wave * 32 + lr;
    f32x16 accz = (f32x16)(0.f);
    const __bf16* wv = WvT + (size_t)col * HID + hi * 8;
#pragma unroll
    for (int kk = 0; kk < 4; ++kk) {
      bf16x8 a = lds_read_bf8(zps, lr, kk * 16 + hi * 8);
      bf16x8 bq = *(const bf16x8*)(wv + kk * 16);
      accz = __builtin_amdgcn_mfma_f32_32x32x16_bf16(a, bq, accz, 0, 0, 0);
    }
    float bvl = bv[col];
#pragma unroll
    for (int reg = 0; reg < 16; ++reg) {
      int rr = (reg & 3) + 8 * (reg >> 2) + 4 * hi;
      zb[(size_t)(row0 + rr) * HID + col] = (__bf16)(accz[reg] + bvl);
    }
  } else if (wave < 6) {
    // x_hat = zp@Wvdx + bvdx (parallel with z-wave work; both read zps only)
    int c0 = (wave - 2) * 32 + lr;
    f32x16 acx = (f32x16)(0.f);
    const __bf16* wd = WvdxT + (size_t)c0 * HID + hi * 8;
#pragma unroll
    for (int kk = 0; kk < 4; ++kk) {
      bf16x8 a = lds_read_bf8(zps, lr, kk * 16 + hi * 8);
      bf16x8 bq = *(const bf16x8*)(wd + kk * 16);
      acx = __builtin_amdgcn_mfma_f32_32x32x16_bf16(a, bq, acx, 0, 0, 0);
    }
    float bdl = bvdx[c0];
#pragma unroll
    for (int reg = 0; reg < 16; ++reg) {
      int rr = (reg & 3) + 8 * (reg >> 2) + 4 * hi;
      xhat[(size_t)(row0 + rr) * IND + c0] = acx[reg] + bdl;
    }
  }
}

// ---------------- K5: adj_hat = z @ z^T via bf16 MFMA (R8 exact) ----------------
__global__ __launch_bounds__(256) void adj_mfma_kernel(
    const __bf16* __restrict__ z, float* __restrict__ out) {
  int tid = threadIdx.x;
  int wave = tid >> 6, lane = tid & 63;
  int wr = wave >> 1, wc = wave & 1;
  int rb = blockIdx.y, cb = blockIdx.x;
  int lr = lane & 31, hi = lane >> 5;

  size_t arow0 = (size_t)(rb * 128 + wr * 64 + lr) * HID;
  size_t arow1 = arow0 + (size_t)32 * HID;
  size_t brow0 = (size_t)(cb * 128 + wc * 64 + lr) * HID;
  size_t brow1 = brow0 + (size_t)32 * HID;
  int kbase = hi * 8;

  f32x16 acc00 = (f32x16)(0.f), acc01 = (f32x16)(0.f);
  f32x16 acc10 = (f32x16)(0.f), acc11 = (f32x16)(0.f);

#pragma unroll
  for (int kk = 0; kk < 4; ++kk) {
    int k0 = kk * 16 + kbase;
    bf16x8 a0 = *(const bf16x8*)(z + arow0 + k0);
    bf16x8 a1 = *(const bf16x8*)(z + arow1 + k0);
    bf16x8 b0 = *(const bf16x8*)(z + brow0 + k0);
    bf16x8 b1 = *(const bf16x8*)(z + brow1 + k0);
    acc00 = __builtin_amdgcn_mfma_f32_32x32x16_bf16(a0, b0, acc00, 0, 0, 0);
    acc01 = __builtin_amdgcn_mfma_f32_32x32x16_bf16(a0, b1, acc01, 0, 0, 0);
    acc10 = __builtin_amdgcn_mfma_f32_32x32x16_bf16(a1, b0, acc10, 0, 0, 0);
    acc11 = __builtin_amdgcn_mfma_f32_32x32x16_bf16(a1, b1, acc11, 0, 0, 0);
  }

  int colb = cb * 128 + wc * 64 + lr;
  int rowb = rb * 128 + wr * 64 + 4 * hi;
#pragma unroll
  for (int reg = 0; reg < 16; ++reg) {
    int rr = (reg & 3) + 8 * (reg >> 2);
    size_t r0 = (size_t)(rowb + rr);
    __builtin_nontemporal_store(acc00[reg], out + r0 * N_ + colb);
    __builtin_nontemporal_store(acc01[reg], out + r0 * N_ + colb + 32);
    __builtin_nontemporal_store(acc10[reg], out + (r0 + 32) * N_ + colb);
    __builtin_nontemporal_store(acc11[reg], out + (r0 + 32) * N_ + colb + 32);
  }
}

extern "C" void kernel_launch(void* const* d_in, const int* in_sizes, int n_in,
                              void* d_out, int out_size, void* d_ws, size_t ws_size,
                              hipStream_t stream) {
  const float* x_train = (const float*)d_in[0];
  const float* x_ori   = (const float*)d_in[1];
  const int*   ei      = (const int*)d_in[2];
  const unsigned char* mask = (const unsigned char*)d_in[3];
  const float* W1  = (const float*)d_in[4];
  const float* b1  = (const float*)d_in[5];
  const float* W2  = (const float*)d_in[6];
  const float* b2  = (const float*)d_in[7];
  const float* Wq  = (const float*)d_in[8];
  const float* bq  = (const float*)d_in[9];
  const float* Wk  = (const float*)d_in[10];
  const float* bk  = (const float*)d_in[11];
  const float* Wv  = (const float*)d_in[12];
  const float* bv  = (const float*)d_in[13];
  const float* Wdx = (const float*)d_in[14];
  const float* bdx = (const float*)d_in[15];

  char* ws = (char*)d_ws;
  size_t o = 0;
  auto alloc = [&](size_t bytes) -> void* {
    void* p = ws + o;
    o += (bytes + 255) & ~(size_t)255;
    return p;
  };
  __bf16* WvT   = (__bf16*)alloc((size_t)HID * HID * 2);
  __bf16* WvdxT = (__bf16*)alloc((size_t)HID * IND * 2);
  float* bvdx   = (float*)alloc((size_t)IND * 4);
  float* h_tr   = (float*)alloc((size_t)N_ * HID * 4);
  float* lap1d  = (float*)alloc((size_t)N_ * HID * 4);
  __bf16* zb    = (__bf16*)alloc((size_t)N_ * HID * 2);
  float* dinv   = (float*)alloc((size_t)N_ * 4);
  int*   csrRow = (int*)alloc((size_t)N_ * CAP * 4);
  int*   zero0  = (int*)alloc((size_t)(2 * N_ + 65) * 4);
  int*   degRow = zero0;
  int*   cntCol = zero0 + N_;
  float* gsum   = (float*)(zero0 + 2 * N_);

  const int* row = ei;
  const int* col = ei + E_;

  (void)hipMemsetAsync(zero0, 0, (size_t)(2 * N_ + 65) * 4, stream);

  fused_front_kernel<<<1154, 256, 0, stream>>>(x_ori, x_train, row, col,
                                               W1, b1, W2, b2, Wv, bv, Wdx, bdx,
                                               mask, WvT, WvdxT, bvdx,
                                               h_tr, gsum, degRow, cntCol, csrRow);
  lap1_kernel<<<N_ / 16, 256, 0, stream>>>(h_tr, degRow, cntCol, csrRow,
                                           lap1d, dinv);

  float* outp = (float*)d_out;
  lap2_attnz_xhat_kernel<<<N_ / 32, 512, 0, stream>>>(h_tr, lap1d, dinv,
                                                      cntCol, csrRow, gsum,
                                                      Wq, bq, Wk, bk, WvT, bv,
                                                      WvdxT, bvdx, outp, zb);
  adj_mfma_kernel<<<dim3(96, 96), 256, 0, stream>>>(zb, outp + (size_t)N_ * IND);
}